// Round 6
// baseline (451.609 us; speedup 1.0000x reference)
//
#include <hip/hip_runtime.h>
#include <cstdint>

// ---------- common helpers ----------

typedef __bf16 bf16x8 __attribute__((ext_vector_type(8)));
typedef float  f32x4  __attribute__((ext_vector_type(4)));
typedef unsigned short u16x8 __attribute__((ext_vector_type(8)));

__device__ __forceinline__ unsigned short f2b(float f) {
    union { float f; unsigned u; } v; v.f = f;
    unsigned r = v.u + 0x7FFFu + ((v.u >> 16) & 1u);   // RNE
    return (unsigned short)(r >> 16);
}

__device__ __forceinline__ float b2f(unsigned short u) {
    union { unsigned u; float f; } v; v.u = ((unsigned)u) << 16;
    return v.f;
}

__device__ __forceinline__ float fast_tanh(float x) {
    float e = __builtin_amdgcn_exp2f(2.885390082f * x);
    return 1.0f - 2.0f * __builtin_amdgcn_rcpf(e + 1.0f);
}

__device__ __forceinline__ void async_copy16(void* lds, const void* g) {
    __builtin_amdgcn_global_load_lds(
        (const __attribute__((address_space(1))) unsigned int*)g,
        (__attribute__((address_space(3))) unsigned int*)lds,
        16, 0, 0);
}

// LDS layout (BK=64 bf16): row r = 8 x 16B chunks; global chunk (r,c) lives at
// elem offset r*64 + ((c^(r&7))<<3). 2-way max bank aliasing (free, m136).

// ---------- conversion kernels ----------

__global__ __launch_bounds__(256) void k_cvt(const float* __restrict__ in,
                                             unsigned short* __restrict__ out) {
    int i = blockIdx.x * 256 + threadIdx.x;
    float4 f = ((const float4*)in)[i];
    ushort4 o = make_ushort4(f2b(f.x), f2b(f.y), f2b(f.z), f2b(f.w));
    ((ushort4*)out)[i] = o;
}

__global__ __launch_bounds__(256) void k_transpose_cvt(const float* __restrict__ in,
                                                       unsigned short* __restrict__ out,
                                                       int R, int C) {
    __shared__ float tile[32][33];
    int bc = blockIdx.x * 32;
    int br = blockIdx.y * 32;
    int tx = threadIdx.x, ty = threadIdx.y;   // (32, 8)
    #pragma unroll
    for (int i = 0; i < 32; i += 8)
        tile[ty + i][tx] = in[(size_t)(br + ty + i) * C + bc + tx];
    __syncthreads();
    #pragma unroll
    for (int i = 0; i < 32; i += 8)
        out[(size_t)(bc + ty + i) * R + br + tx] = f2b(tile[tx][ty + i]);
}

// ---------- GEMM1: 512-thread 128x128 tile, BK=64, bias+tanh -> bf16 ----------

__global__ __launch_bounds__(512, 4)
void k_gemm_tanh(const unsigned short* __restrict__ A,
                 const unsigned short* __restrict__ B,
                 const float* __restrict__ bias,
                 unsigned short* __restrict__ Out, int ldout,
                 int lda, int ldb, int k_len) {
    __shared__ __align__(16) unsigned short As[128 * 64];
    __shared__ __align__(16) unsigned short Bs[128 * 64];

    const int tid  = threadIdx.x;
    const int wave = tid >> 6;
    const int lane = tid & 63;
    const int quad = lane >> 4;
    const int l16  = lane & 15;
    const int wr   = wave >> 2;
    const int wc   = wave & 3;

    const int bid = blockIdx.x;
    const int xcd = bid & 7;
    const int lid = bid >> 3;
    const int bn  = lid & 7;
    const int bm  = (lid >> 3) * 8 + xcd;

    const unsigned short* Ag = A + (size_t)(bm * 128) * lda;
    const unsigned short* Bg = B + (size_t)(bn * 128) * ldb;

    f32x4 acc[4][2];
    #pragma unroll
    for (int i = 0; i < 4; i++)
        #pragma unroll
        for (int j = 0; j < 2; j++)
            acc[i][j] = f32x4{0.f, 0.f, 0.f, 0.f};

    int sr[2], sc[2];
    #pragma unroll
    for (int j = 0; j < 2; j++) {
        int q = j * 512 + wave * 64 + lane;
        sr[j] = q >> 3;
        sc[j] = ((q & 7) ^ (sr[j] & 7)) << 3;
    }

    int roA[4], coA[4], roB[2], coB[2];
    #pragma unroll
    for (int i = 0; i < 4; i++) {
        int r = wr * 64 + i * 16 + l16;
        roA[i] = r * 64; coA[i] = quad ^ (r & 7);
    }
    #pragma unroll
    for (int j = 0; j < 2; j++) {
        int r = wc * 32 + j * 16 + l16;
        roB[j] = r * 64; coB[j] = quad ^ (r & 7);
    }

    for (int k0 = 0; k0 < k_len; k0 += 64) {
        #pragma unroll
        for (int j = 0; j < 2; j++) {
            async_copy16(&As[(j * 512 + wave * 64) * 8], Ag + (size_t)sr[j] * lda + k0 + sc[j]);
            async_copy16(&Bs[(j * 512 + wave * 64) * 8], Bg + (size_t)sr[j] * ldb + k0 + sc[j]);
        }
        asm volatile("s_waitcnt vmcnt(0)" ::: "memory");
        __syncthreads();

        #pragma unroll
        for (int s = 0; s < 2; s++) {
            bf16x8 av[4], bv[2];
            #pragma unroll
            for (int i = 0; i < 4; i++)
                av[i] = *(const bf16x8*)&As[roA[i] + ((coA[i] ^ (s << 2)) << 3)];
            #pragma unroll
            for (int j = 0; j < 2; j++)
                bv[j] = *(const bf16x8*)&Bs[roB[j] + ((coB[j] ^ (s << 2)) << 3)];
            #pragma unroll
            for (int i = 0; i < 4; i++)
                #pragma unroll
                for (int j = 0; j < 2; j++)
                    acc[i][j] = __builtin_amdgcn_mfma_f32_16x16x32_bf16(av[i], bv[j], acc[i][j], 0, 0, 0);
        }
        __syncthreads();
    }

    #pragma unroll
    for (int i = 0; i < 4; i++) {
        int rbase = bm * 128 + wr * 64 + i * 16 + quad * 4;
        #pragma unroll
        for (int j = 0; j < 2; j++) {
            int col = bn * 128 + wc * 32 + j * 16 + l16;
            float bc = bias[col];
            #pragma unroll
            for (int r = 0; r < 4; r++)
                Out[(size_t)(rbase + r) * ldout + col] = f2b(fast_tanh(acc[i][j][r] + bc));
        }
    }
}

// ---------- GEMM2: 256-thread 128x128, BK=64, +bias -> bf16, XCD-swizzled ----------

template <int LBN>
__global__ __launch_bounds__(256, 3)
void k_gemm(const unsigned short* __restrict__ A,
            const unsigned short* __restrict__ B,
            const float* __restrict__ bias,
            unsigned short* __restrict__ Out, int ldout,
            int lda, int ldb, int k_len) {
    __shared__ __align__(16) unsigned short As[128 * 64];
    __shared__ __align__(16) unsigned short Bs[128 * 64];

    const int tid  = threadIdx.x;
    const int wave = tid >> 6;
    const int lane = tid & 63;
    const int quad = lane >> 4;
    const int l16  = lane & 15;
    const int wr   = wave >> 1;
    const int wc   = wave & 1;

    const int bid = blockIdx.x;
    const int xcd = bid & 7;
    const int lid = bid >> 3;
    const int bn = lid & ((1 << LBN) - 1);
    const int bm = (lid >> LBN) * 8 + xcd;

    const unsigned short* Ag = A + (size_t)(bm * 128) * lda;
    const unsigned short* Bg = B + (size_t)(bn * 128) * ldb;

    f32x4 acc[4][4];
    #pragma unroll
    for (int i = 0; i < 4; i++)
        #pragma unroll
        for (int j = 0; j < 4; j++)
            acc[i][j] = f32x4{0.f, 0.f, 0.f, 0.f};

    int sr[4], sc[4];
    #pragma unroll
    for (int j = 0; j < 4; j++) {
        int q = j * 256 + wave * 64 + lane;
        sr[j] = q >> 3;
        sc[j] = ((q & 7) ^ (sr[j] & 7)) << 3;
    }

    int roA[4], coA[4], roB[4], coB[4];
    #pragma unroll
    for (int i = 0; i < 4; i++) {
        int ra = wr * 64 + i * 16 + l16;
        roA[i] = ra * 64; coA[i] = quad ^ (ra & 7);
        int rb = wc * 64 + i * 16 + l16;
        roB[i] = rb * 64; coB[i] = quad ^ (rb & 7);
    }

    for (int k0 = 0; k0 < k_len; k0 += 64) {
        #pragma unroll
        for (int j = 0; j < 4; j++) {
            async_copy16(&As[(j * 256 + wave * 64) * 8], Ag + (size_t)sr[j] * lda + k0 + sc[j]);
            async_copy16(&Bs[(j * 256 + wave * 64) * 8], Bg + (size_t)sr[j] * ldb + k0 + sc[j]);
        }
        asm volatile("s_waitcnt vmcnt(0)" ::: "memory");
        __syncthreads();

        #pragma unroll
        for (int s = 0; s < 2; s++) {
            bf16x8 av[4], bv[4];
            #pragma unroll
            for (int i = 0; i < 4; i++)
                av[i] = *(const bf16x8*)&As[roA[i] + ((coA[i] ^ (s << 2)) << 3)];
            #pragma unroll
            for (int j = 0; j < 4; j++)
                bv[j] = *(const bf16x8*)&Bs[roB[j] + ((coB[j] ^ (s << 2)) << 3)];
            #pragma unroll
            for (int i = 0; i < 4; i++)
                #pragma unroll
                for (int j = 0; j < 4; j++)
                    acc[i][j] = __builtin_amdgcn_mfma_f32_16x16x32_bf16(av[i], bv[j], acc[i][j], 0, 0, 0);
        }
        __syncthreads();
    }

    #pragma unroll
    for (int i = 0; i < 4; i++) {
        int rbase = bm * 128 + wr * 64 + i * 16 + quad * 4;
        #pragma unroll
        for (int j = 0; j < 4; j++) {
            int col = bn * 128 + wc * 64 + j * 16 + l16;
            float bc = bias[col];
            #pragma unroll
            for (int r = 0; r < 4; r++)
                Out[(size_t)(rbase + r) * ldout + col] = f2b(acc[i][j][r] + bc);
        }
    }
}

// ---------- sparsemax tau only: one WAVE per row, writes tau[row] ----------
__global__ __launch_bounds__(256)
void k_sparsemax_tau(const unsigned short* __restrict__ a,
                     float* __restrict__ tau_out) {
    const int wave = threadIdx.x >> 6;
    const int lane = threadIdx.x & 63;
    const int row = blockIdx.x * 4 + wave;

    const u16x8* ar = (const u16x8*)(a + (size_t)row * 4096);
    float v[64];
    #pragma unroll
    for (int j = 0; j < 8; j++) {
        u16x8 u = ar[lane + 64 * j];
        #pragma unroll
        for (int k = 0; k < 8; k++) v[j * 8 + k] = b2f(u[k]);
    }

    float m = v[0];
    #pragma unroll
    for (int i = 1; i < 64; i++) m = fmaxf(m, v[i]);
    #pragma unroll
    for (int off = 1; off < 64; off <<= 1) m = fmaxf(m, __shfl_xor(m, off));

    float lo = m - 1.0f, hi = m;
    #pragma unroll 1
    for (int it = 0; it < 14; ++it) {
        float mid = 0.5f * (lo + hi);
        float s = 0.f;
        #pragma unroll
        for (int i = 0; i < 64; i++) s += fmaxf(v[i] - mid, 0.f);
        #pragma unroll
        for (int off = 1; off < 64; off <<= 1) s += __shfl_xor(s, off);
        if (s > 1.0f) lo = mid; else hi = mid;
    }
    if (lane == 0) tau_out[row] = 0.5f * (lo + hi);
}

// ---------- GEMM3 fused gating: P[kz] = (x*max(a-tau,0)) @ Wc1, split-K ----------
// grid (bm=64, kz=8); stages xb + abf + Wc1t tiles (48 KB LDS).

__global__ __launch_bounds__(256)
void k_gemm3(const unsigned short* __restrict__ X,
             const unsigned short* __restrict__ Aa,
             const unsigned short* __restrict__ B,
             const float* __restrict__ tau,
             float* __restrict__ P, int k_len) {
    __shared__ __align__(16) unsigned short Xs[128 * 64];
    __shared__ __align__(16) unsigned short As[128 * 64];
    __shared__ __align__(16) unsigned short Bs[128 * 64];

    const int tid  = threadIdx.x;
    const int wave = tid >> 6;
    const int lane = tid & 63;
    const int quad = lane >> 4;
    const int l16  = lane & 15;
    const int wr   = wave >> 1;
    const int wc   = wave & 1;

    const int bm = blockIdx.x;
    const int kz = blockIdx.y;

    const unsigned short* Xg = X  + (size_t)(bm * 128) * 4096 + (size_t)kz * k_len;
    const unsigned short* Ag = Aa + (size_t)(bm * 128) * 4096 + (size_t)kz * k_len;
    const unsigned short* Bg = B  + (size_t)kz * k_len;   // Wc1t rows 0..127

    f32x4 acc[4][4];
    #pragma unroll
    for (int i = 0; i < 4; i++)
        #pragma unroll
        for (int j = 0; j < 4; j++)
            acc[i][j] = f32x4{0.f, 0.f, 0.f, 0.f};

    int sr[4], sc[4];
    #pragma unroll
    for (int j = 0; j < 4; j++) {
        int q = j * 256 + wave * 64 + lane;
        sr[j] = q >> 3;
        sc[j] = ((q & 7) ^ (sr[j] & 7)) << 3;
    }

    int roA[4], coA[4], roB[4], coB[4];
    float t4[4];
    #pragma unroll
    for (int i = 0; i < 4; i++) {
        int ra = wr * 64 + i * 16 + l16;
        roA[i] = ra * 64; coA[i] = quad ^ (ra & 7);
        t4[i] = tau[bm * 128 + ra];
        int rb = wc * 64 + i * 16 + l16;
        roB[i] = rb * 64; coB[i] = quad ^ (rb & 7);
    }

    for (int k0 = 0; k0 < k_len; k0 += 64) {
        #pragma unroll
        for (int j = 0; j < 4; j++) {
            async_copy16(&Xs[(j * 256 + wave * 64) * 8], Xg + (size_t)sr[j] * 4096 + k0 + sc[j]);
            async_copy16(&As[(j * 256 + wave * 64) * 8], Ag + (size_t)sr[j] * 4096 + k0 + sc[j]);
            async_copy16(&Bs[(j * 256 + wave * 64) * 8], Bg + (size_t)sr[j] * 4096 + k0 + sc[j]);
        }
        asm volatile("s_waitcnt vmcnt(0)" ::: "memory");
        __syncthreads();

        #pragma unroll
        for (int s = 0; s < 2; s++) {
            bf16x8 av[4], bv[4];
            #pragma unroll
            for (int i = 0; i < 4; i++) {
                u16x8 xa = *(const u16x8*)&Xs[roA[i] + ((coA[i] ^ (s << 2)) << 3)];
                u16x8 aa = *(const u16x8*)&As[roA[i] + ((coA[i] ^ (s << 2)) << 3)];
                union { unsigned u[4]; bf16x8 v; } wpk;
                #pragma unroll
                for (int e = 0; e < 4; e++) {
                    float w0 = fmaxf(b2f(aa[2 * e])     - t4[i], 0.f) * b2f(xa[2 * e]);
                    float w1 = fmaxf(b2f(aa[2 * e + 1]) - t4[i], 0.f) * b2f(xa[2 * e + 1]);
                    wpk.u[e] = __builtin_amdgcn_perm(__float_as_uint(w1), __float_as_uint(w0),
                                                     0x07060302u);   // truncate-pack 2 bf16
                }
                av[i] = wpk.v;
            }
            #pragma unroll
            for (int j = 0; j < 4; j++)
                bv[j] = *(const bf16x8*)&Bs[roB[j] + ((coB[j] ^ (s << 2)) << 3)];
            #pragma unroll
            for (int i = 0; i < 4; i++)
                #pragma unroll
                for (int j = 0; j < 4; j++)
                    acc[i][j] = __builtin_amdgcn_mfma_f32_16x16x32_bf16(av[i], bv[j], acc[i][j], 0, 0, 0);
        }
        __syncthreads();
    }

    #pragma unroll
    for (int i = 0; i < 4; i++) {
        int rbase = bm * 128 + wr * 64 + i * 16 + quad * 4;
        #pragma unroll
        for (int j = 0; j < 4; j++) {
            int col = wc * 64 + j * 16 + l16;
            #pragma unroll
            for (int r = 0; r < 4; r++)
                P[(size_t)kz * 8192 * 128 + (size_t)(rbase + r) * 128 + col] = acc[i][j][r];
        }
    }
}

// ---------- final: out = relu(sum_p P[p] + bc1) @ Wc2 + bc2 ----------
__global__ __launch_bounds__(256)
void k_final(const float* __restrict__ P, const float* __restrict__ bc1,
             const float* __restrict__ Wc2, const float* __restrict__ bc2,
             float* __restrict__ out) {
    __shared__ float w2s[128 * 16];
    __shared__ float hs[4 * 128];
    const int tid = threadIdx.x;
    for (int i = tid; i < 2048; i += 256) w2s[i] = Wc2[i];

    #pragma unroll
    for (int i = tid; i < 512; i += 256) {
        int r = i >> 7, c = i & 127;
        int row = blockIdx.x * 4 + r;
        float s = bc1[c];
        #pragma unroll
        for (int p = 0; p < 8; p++)
            s += P[((size_t)p * 8192 + row) * 128 + c];
        hs[i] = fmaxf(s, 0.f);
    }
    __syncthreads();

    const int wave = tid >> 6, lane = tid & 63;
    const int row = blockIdx.x * 4 + wave;
    const int c = lane & 15, hq = lane >> 4;
    float acc = 0.f;
    #pragma unroll
    for (int t = 0; t < 32; ++t) {
        int hidx = hq * 32 + t;
        acc += hs[wave * 128 + hidx] * w2s[hidx * 16 + c];
    }
    acc += __shfl_xor(acc, 16);
    acc += __shfl_xor(acc, 32);
    if (hq == 0) out[(size_t)row * 16 + c] = acc + bc2[c];
}

// ---------- launch ----------

extern "C" void kernel_launch(void* const* d_in, const int* in_sizes, int n_in,
                              void* d_out, int out_size, void* d_ws, size_t ws_size,
                              hipStream_t stream) {
    (void)in_sizes; (void)n_in; (void)out_size; (void)ws_size;
    const float* x   = (const float*)d_in[0];
    const float* W1  = (const float*)d_in[1];
    const float* b1  = (const float*)d_in[2];
    const float* W2  = (const float*)d_in[3];
    const float* b2  = (const float*)d_in[4];
    const float* Wc1 = (const float*)d_in[5];
    const float* bc1 = (const float*)d_in[6];
    const float* Wc2 = (const float*)d_in[7];
    const float* bc2 = (const float*)d_in[8];
    float* out = (float*)d_out;

    char* ws = (char*)d_ws;
    unsigned short* xb   = (unsigned short*)(ws);                  // 0..64 MB   x bf16 (live thru GEMM3)
    unsigned short* W1t  = (unsigned short*)(ws + (64ll  << 20));  // 64..72
    unsigned short* Tb   = (unsigned short*)(ws + (72ll  << 20));  // 72..88
    unsigned short* W2t  = (unsigned short*)(ws + (88ll  << 20));  // 88..96
    unsigned short* abf  = (unsigned short*)(ws + (96ll  << 20));  // 96..160    a bf16 (live thru GEMM3)
    unsigned short* Wc1t = (unsigned short*)(ws + (160ll << 20));  // 160..161
    float*          taub = (float*)         (ws + (162ll << 20));  // 162..162.03 (8192 fp32)
    float*          P3   = (float*)         (ws + (168ll << 20));  // 168..200   GEMM3 partials (8x4MB)

    dim3 tb(32, 8);
    k_cvt<<<32768, 256, 0, stream>>>(x, xb);
    k_transpose_cvt<<<dim3(1024 / 32, 4096 / 32), tb, 0, stream>>>(W1, W1t, 4096, 1024);
    k_transpose_cvt<<<dim3(4096 / 32, 1024 / 32), tb, 0, stream>>>(W2, W2t, 1024, 4096);
    k_transpose_cvt<<<dim3(128 / 32, 4096 / 32), tb, 0, stream>>>(Wc1, Wc1t, 4096, 128);

    // T = tanh(x @ W1 + b1)  [8192][1024] bf16 — XCD-swizzled, BK=64
    k_gemm_tanh<<<512, 512, 0, stream>>>(xb, W1t, b1, Tb, 1024, 4096, 4096, 4096);
    // a = T @ W2 + b2  [8192][4096] bf16 — XCD-swizzled (LBN=5)
    k_gemm<5><<<2048, 256, 0, stream>>>(Tb, W2t, b2, abf, 4096, 1024, 1024, 1024);
    // tau per row (sparsemax threshold)
    k_sparsemax_tau<<<2048, 256, 0, stream>>>(abf, taub);
    // P3[kz] = (x * max(a - tau, 0)) @ Wc1, split-K=8, gating fused
    k_gemm3<<<dim3(64, 8), 256, 0, stream>>>(xb, abf, Wc1t, taub, P3, 512);
    // out = relu(sum P3 + bc1) @ Wc2 + bc2
    k_final<<<2048, 256, 0, stream>>>(P3, bc1, Wc2, bc2, out);
}

// Round 7
// 436.558 us; speedup vs baseline: 1.0345x; 1.0345x over previous
//
#include <hip/hip_runtime.h>
#include <cstdint>

// ---------- common helpers ----------

typedef __bf16 bf16x8 __attribute__((ext_vector_type(8)));
typedef float  f32x4  __attribute__((ext_vector_type(4)));
typedef unsigned short u16x8 __attribute__((ext_vector_type(8)));

__device__ __forceinline__ unsigned short f2b(float f) {
    union { float f; unsigned u; } v; v.f = f;
    unsigned r = v.u + 0x7FFFu + ((v.u >> 16) & 1u);   // RNE
    return (unsigned short)(r >> 16);
}

__device__ __forceinline__ float b2f(unsigned short u) {
    union { unsigned u; float f; } v; v.u = ((unsigned)u) << 16;
    return v.f;
}

__device__ __forceinline__ float fast_tanh(float x) {
    float e = __builtin_amdgcn_exp2f(2.885390082f * x);
    return 1.0f - 2.0f * __builtin_amdgcn_rcpf(e + 1.0f);
}

__device__ __forceinline__ void async_copy16(void* lds, const void* g) {
    __builtin_amdgcn_global_load_lds(
        (const __attribute__((address_space(1))) unsigned int*)g,
        (__attribute__((address_space(3))) unsigned int*)lds,
        16, 0, 0);
}

// LDS layout (BK=64 bf16): row r = 8 x 16B chunks; global chunk (r,c) lives at
// elem offset r*64 + ((c^(r&7))<<3). 2-way max bank aliasing (free, m136).

// ---------- k_pre: fused x->bf16 cvt + 3 weight transposes ----------
// blocks [0,32768): cvt; [32768,36864): W1; [36864,40960): W2; [40960,41472): Wc1

__global__ __launch_bounds__(256)
void k_pre(const float* __restrict__ x, unsigned short* __restrict__ xb,
           const float* __restrict__ W1, unsigned short* __restrict__ W1t,
           const float* __restrict__ W2, unsigned short* __restrict__ W2t,
           const float* __restrict__ Wc1, unsigned short* __restrict__ Wc1t) {
    const int tid = threadIdx.x;
    int b = blockIdx.x;
    if (b < 32768) {
        int i = b * 256 + tid;
        float4 f = ((const float4*)x)[i];
        ((ushort4*)xb)[i] = make_ushort4(f2b(f.x), f2b(f.y), f2b(f.z), f2b(f.w));
        return;
    }
    b -= 32768;
    const float* in; unsigned short* outp; int R, C, bx, by;
    if (b < 4096)      { in = W1;  outp = W1t;  R = 4096; C = 1024; bx = b & 31;  by = b >> 5; }
    else if (b < 8192) { b -= 4096; in = W2;  outp = W2t;  R = 1024; C = 4096; bx = b & 127; by = b >> 7; }
    else               { b -= 8192; in = Wc1; outp = Wc1t; R = 4096; C = 128;  bx = b & 3;   by = b >> 2; }
    __shared__ float tile[32][33];
    int bc = bx * 32, br = by * 32;
    int tx = tid & 31, ty = tid >> 5;   // (32, 8)
    #pragma unroll
    for (int i = 0; i < 32; i += 8)
        tile[ty + i][tx] = in[(size_t)(br + ty + i) * C + bc + tx];
    __syncthreads();
    #pragma unroll
    for (int i = 0; i < 32; i += 8)
        outp[(size_t)(bc + ty + i) * R + br + tx] = f2b(tile[tx][ty + i]);
}

// ---------- GEMM1: 512-thread 128x128 tile, BK=64, bias+tanh -> bf16 ----------

__global__ __launch_bounds__(512, 4)
void k_gemm_tanh(const unsigned short* __restrict__ A,
                 const unsigned short* __restrict__ B,
                 const float* __restrict__ bias,
                 unsigned short* __restrict__ Out, int ldout,
                 int lda, int ldb, int k_len) {
    __shared__ __align__(16) unsigned short As[128 * 64];
    __shared__ __align__(16) unsigned short Bs[128 * 64];

    const int tid  = threadIdx.x;
    const int wave = tid >> 6;
    const int lane = tid & 63;
    const int quad = lane >> 4;
    const int l16  = lane & 15;
    const int wr   = wave >> 2;
    const int wc   = wave & 3;

    const int bid = blockIdx.x;
    const int xcd = bid & 7;
    const int lid = bid >> 3;
    const int bn  = lid & 7;
    const int bm  = (lid >> 3) * 8 + xcd;

    const unsigned short* Ag = A + (size_t)(bm * 128) * lda;
    const unsigned short* Bg = B + (size_t)(bn * 128) * ldb;

    f32x4 acc[4][2];
    #pragma unroll
    for (int i = 0; i < 4; i++)
        #pragma unroll
        for (int j = 0; j < 2; j++)
            acc[i][j] = f32x4{0.f, 0.f, 0.f, 0.f};

    int sr[2], sc[2];
    #pragma unroll
    for (int j = 0; j < 2; j++) {
        int q = j * 512 + wave * 64 + lane;
        sr[j] = q >> 3;
        sc[j] = ((q & 7) ^ (sr[j] & 7)) << 3;
    }

    int roA[4], coA[4], roB[2], coB[2];
    #pragma unroll
    for (int i = 0; i < 4; i++) {
        int r = wr * 64 + i * 16 + l16;
        roA[i] = r * 64; coA[i] = quad ^ (r & 7);
    }
    #pragma unroll
    for (int j = 0; j < 2; j++) {
        int r = wc * 32 + j * 16 + l16;
        roB[j] = r * 64; coB[j] = quad ^ (r & 7);
    }

    for (int k0 = 0; k0 < k_len; k0 += 64) {
        #pragma unroll
        for (int j = 0; j < 2; j++) {
            async_copy16(&As[(j * 512 + wave * 64) * 8], Ag + (size_t)sr[j] * lda + k0 + sc[j]);
            async_copy16(&Bs[(j * 512 + wave * 64) * 8], Bg + (size_t)sr[j] * ldb + k0 + sc[j]);
        }
        asm volatile("s_waitcnt vmcnt(0)" ::: "memory");
        __syncthreads();

        #pragma unroll
        for (int s = 0; s < 2; s++) {
            bf16x8 av[4], bv[2];
            #pragma unroll
            for (int i = 0; i < 4; i++)
                av[i] = *(const bf16x8*)&As[roA[i] + ((coA[i] ^ (s << 2)) << 3)];
            #pragma unroll
            for (int j = 0; j < 2; j++)
                bv[j] = *(const bf16x8*)&Bs[roB[j] + ((coB[j] ^ (s << 2)) << 3)];
            #pragma unroll
            for (int i = 0; i < 4; i++)
                #pragma unroll
                for (int j = 0; j < 2; j++)
                    acc[i][j] = __builtin_amdgcn_mfma_f32_16x16x32_bf16(av[i], bv[j], acc[i][j], 0, 0, 0);
        }
        __syncthreads();
    }

    #pragma unroll
    for (int i = 0; i < 4; i++) {
        int rbase = bm * 128 + wr * 64 + i * 16 + quad * 4;
        #pragma unroll
        for (int j = 0; j < 2; j++) {
            int col = bn * 128 + wc * 32 + j * 16 + l16;
            float bc = bias[col];
            #pragma unroll
            for (int r = 0; r < 4; r++)
                Out[(size_t)(rbase + r) * ldout + col] = f2b(fast_tanh(acc[i][j][r] + bc));
        }
    }
}

// ---------- GEMM2: 256-thread 128x128, BK=64, +bias -> bf16, XCD-swizzled ----------

template <int LBN>
__global__ __launch_bounds__(256, 3)
void k_gemm(const unsigned short* __restrict__ A,
            const unsigned short* __restrict__ B,
            const float* __restrict__ bias,
            unsigned short* __restrict__ Out, int ldout,
            int lda, int ldb, int k_len) {
    __shared__ __align__(16) unsigned short As[128 * 64];
    __shared__ __align__(16) unsigned short Bs[128 * 64];

    const int tid  = threadIdx.x;
    const int wave = tid >> 6;
    const int lane = tid & 63;
    const int quad = lane >> 4;
    const int l16  = lane & 15;
    const int wr   = wave >> 1;
    const int wc   = wave & 1;

    const int bid = blockIdx.x;
    const int xcd = bid & 7;
    const int lid = bid >> 3;
    const int bn = lid & ((1 << LBN) - 1);
    const int bm = (lid >> LBN) * 8 + xcd;

    const unsigned short* Ag = A + (size_t)(bm * 128) * lda;
    const unsigned short* Bg = B + (size_t)(bn * 128) * ldb;

    f32x4 acc[4][4];
    #pragma unroll
    for (int i = 0; i < 4; i++)
        #pragma unroll
        for (int j = 0; j < 4; j++)
            acc[i][j] = f32x4{0.f, 0.f, 0.f, 0.f};

    int sr[4], sc[4];
    #pragma unroll
    for (int j = 0; j < 4; j++) {
        int q = j * 256 + wave * 64 + lane;
        sr[j] = q >> 3;
        sc[j] = ((q & 7) ^ (sr[j] & 7)) << 3;
    }

    int roA[4], coA[4], roB[4], coB[4];
    #pragma unroll
    for (int i = 0; i < 4; i++) {
        int ra = wr * 64 + i * 16 + l16;
        roA[i] = ra * 64; coA[i] = quad ^ (ra & 7);
        int rb = wc * 64 + i * 16 + l16;
        roB[i] = rb * 64; coB[i] = quad ^ (rb & 7);
    }

    for (int k0 = 0; k0 < k_len; k0 += 64) {
        #pragma unroll
        for (int j = 0; j < 4; j++) {
            async_copy16(&As[(j * 256 + wave * 64) * 8], Ag + (size_t)sr[j] * lda + k0 + sc[j]);
            async_copy16(&Bs[(j * 256 + wave * 64) * 8], Bg + (size_t)sr[j] * ldb + k0 + sc[j]);
        }
        asm volatile("s_waitcnt vmcnt(0)" ::: "memory");
        __syncthreads();

        #pragma unroll
        for (int s = 0; s < 2; s++) {
            bf16x8 av[4], bv[4];
            #pragma unroll
            for (int i = 0; i < 4; i++)
                av[i] = *(const bf16x8*)&As[roA[i] + ((coA[i] ^ (s << 2)) << 3)];
            #pragma unroll
            for (int j = 0; j < 4; j++)
                bv[j] = *(const bf16x8*)&Bs[roB[j] + ((coB[j] ^ (s << 2)) << 3)];
            #pragma unroll
            for (int i = 0; i < 4; i++)
                #pragma unroll
                for (int j = 0; j < 4; j++)
                    acc[i][j] = __builtin_amdgcn_mfma_f32_16x16x32_bf16(av[i], bv[j], acc[i][j], 0, 0, 0);
        }
        __syncthreads();
    }

    #pragma unroll
    for (int i = 0; i < 4; i++) {
        int rbase = bm * 128 + wr * 64 + i * 16 + quad * 4;
        #pragma unroll
        for (int j = 0; j < 4; j++) {
            int col = bn * 128 + wc * 64 + j * 16 + l16;
            float bc = bias[col];
            #pragma unroll
            for (int r = 0; r < 4; r++)
                Out[(size_t)(rbase + r) * ldout + col] = f2b(acc[i][j][r] + bc);
        }
    }
}

// ---------- sparsemax tau only: one WAVE per row, writes tau[row] ----------
__global__ __launch_bounds__(256)
void k_sparsemax_tau(const unsigned short* __restrict__ a,
                     float* __restrict__ tau_out) {
    const int wave = threadIdx.x >> 6;
    const int lane = threadIdx.x & 63;
    const int row = blockIdx.x * 4 + wave;

    const u16x8* ar = (const u16x8*)(a + (size_t)row * 4096);
    float v[64];
    #pragma unroll
    for (int j = 0; j < 8; j++) {
        u16x8 u = ar[lane + 64 * j];
        #pragma unroll
        for (int k = 0; k < 8; k++) v[j * 8 + k] = b2f(u[k]);
    }

    float m = v[0];
    #pragma unroll
    for (int i = 1; i < 64; i++) m = fmaxf(m, v[i]);
    #pragma unroll
    for (int off = 1; off < 64; off <<= 1) m = fmaxf(m, __shfl_xor(m, off));

    float lo = m - 1.0f, hi = m;
    #pragma unroll 1
    for (int it = 0; it < 14; ++it) {
        float mid = 0.5f * (lo + hi);
        float s = 0.f;
        #pragma unroll
        for (int i = 0; i < 64; i++) s += fmaxf(v[i] - mid, 0.f);
        #pragma unroll
        for (int off = 1; off < 64; off <<= 1) s += __shfl_xor(s, off);
        if (s > 1.0f) lo = mid; else hi = mid;
    }
    if (lane == 0) tau_out[row] = 0.5f * (lo + hi);
}

// ---------- GEMM3 v2: P[kz] = (x*max(a-tau,0)) @ Wc1, split-K=8 ----------
// N=128 => X/A have ZERO cross-wave reuse: load fragments global->VGPR,
// gate in registers. Only Wc1t (shared) goes through LDS (16 KB).

__global__ __launch_bounds__(256)
void k_gemm3(const unsigned short* __restrict__ X,
             const unsigned short* __restrict__ Aa,
             const unsigned short* __restrict__ B,
             const float* __restrict__ tau,
             float* __restrict__ P) {
    __shared__ __align__(16) unsigned short Bs[128 * 64];

    const int tid  = threadIdx.x;
    const int wave = tid >> 6;
    const int lane = tid & 63;
    const int quad = lane >> 4;
    const int l16  = lane & 15;
    const int wr   = wave >> 1;
    const int wc   = wave & 1;

    const int bm = blockIdx.x;
    const int kz = blockIdx.y;
    const int kbase = kz * 512;

    f32x4 acc[4][4];
    #pragma unroll
    for (int i = 0; i < 4; i++)
        #pragma unroll
        for (int j = 0; j < 4; j++)
            acc[i][j] = f32x4{0.f, 0.f, 0.f, 0.f};

    // B staging: 1024 chunks, 256 threads -> 4 issues each
    int sr[4], sc[4];
    #pragma unroll
    for (int j = 0; j < 4; j++) {
        int q = j * 256 + wave * 64 + lane;
        sr[j] = q >> 3;
        sc[j] = ((q & 7) ^ (sr[j] & 7)) << 3;
    }

    // per-fragment global pointers + tau
    const unsigned short *gx[4], *ga[4];
    float t4[4];
    int roB[4], coB[4];
    #pragma unroll
    for (int i = 0; i < 4; i++) {
        int ra = wr * 64 + i * 16 + l16;
        int row = bm * 128 + ra;
        t4[i] = tau[row];
        gx[i] = X  + (size_t)row * 4096 + kbase + quad * 8;
        ga[i] = Aa + (size_t)row * 4096 + kbase + quad * 8;
        int rb = wc * 64 + i * 16 + l16;
        roB[i] = rb * 64; coB[i] = quad ^ (rb & 7);
    }

    for (int k0 = 0; k0 < 512; k0 += 64) {
        #pragma unroll
        for (int j = 0; j < 4; j++)
            async_copy16(&Bs[(j * 256 + wave * 64) * 8], B + (size_t)sr[j] * 4096 + kbase + k0 + sc[j]);

        u16x8 xf[4][2], af[4][2];
        #pragma unroll
        for (int i = 0; i < 4; i++)
            #pragma unroll
            for (int s = 0; s < 2; s++) {
                xf[i][s] = *(const u16x8*)(gx[i] + k0 + s * 32);
                af[i][s] = *(const u16x8*)(ga[i] + k0 + s * 32);
            }
        asm volatile("s_waitcnt vmcnt(0)" ::: "memory");
        __syncthreads();

        #pragma unroll
        for (int s = 0; s < 2; s++) {
            bf16x8 av[4], bv[4];
            #pragma unroll
            for (int i = 0; i < 4; i++) {
                union { unsigned u[4]; bf16x8 v; } wpk;
                #pragma unroll
                for (int e = 0; e < 4; e++) {
                    float w0 = fmaxf(b2f(af[i][s][2 * e])     - t4[i], 0.f) * b2f(xf[i][s][2 * e]);
                    float w1 = fmaxf(b2f(af[i][s][2 * e + 1]) - t4[i], 0.f) * b2f(xf[i][s][2 * e + 1]);
                    wpk.u[e] = __builtin_amdgcn_perm(__float_as_uint(w1), __float_as_uint(w0),
                                                     0x07060302u);   // truncate-pack 2 bf16
                }
                av[i] = wpk.v;
            }
            #pragma unroll
            for (int j = 0; j < 4; j++)
                bv[j] = *(const bf16x8*)&Bs[roB[j] + ((coB[j] ^ (s << 2)) << 3)];
            #pragma unroll
            for (int i = 0; i < 4; i++)
                #pragma unroll
                for (int j = 0; j < 4; j++)
                    acc[i][j] = __builtin_amdgcn_mfma_f32_16x16x32_bf16(av[i], bv[j], acc[i][j], 0, 0, 0);
        }
        __syncthreads();
    }

    #pragma unroll
    for (int i = 0; i < 4; i++) {
        int rbase = bm * 128 + wr * 64 + i * 16 + quad * 4;
        #pragma unroll
        for (int j = 0; j < 4; j++) {
            int col = wc * 64 + j * 16 + l16;
            #pragma unroll
            for (int r = 0; r < 4; r++)
                P[(size_t)kz * 8192 * 128 + (size_t)(rbase + r) * 128 + col] = acc[i][j][r];
        }
    }
}

// ---------- final: out = relu(sum_p P[p] + bc1) @ Wc2 + bc2 ----------
__global__ __launch_bounds__(256)
void k_final(const float* __restrict__ P, const float* __restrict__ bc1,
             const float* __restrict__ Wc2, const float* __restrict__ bc2,
             float* __restrict__ out) {
    __shared__ float w2s[128 * 16];
    __shared__ float hs[4 * 128];
    const int tid = threadIdx.x;
    for (int i = tid; i < 2048; i += 256) w2s[i] = Wc2[i];

    #pragma unroll
    for (int i = tid; i < 512; i += 256) {
        int r = i >> 7, c = i & 127;
        int row = blockIdx.x * 4 + r;
        float s = bc1[c];
        #pragma unroll
        for (int p = 0; p < 8; p++)
            s += P[((size_t)p * 8192 + row) * 128 + c];
        hs[i] = fmaxf(s, 0.f);
    }
    __syncthreads();

    const int wave = tid >> 6, lane = tid & 63;
    const int row = blockIdx.x * 4 + wave;
    const int c = lane & 15, hq = lane >> 4;
    float acc = 0.f;
    #pragma unroll
    for (int t = 0; t < 32; ++t) {
        int hidx = hq * 32 + t;
        acc += hs[wave * 128 + hidx] * w2s[hidx * 16 + c];
    }
    acc += __shfl_xor(acc, 16);
    acc += __shfl_xor(acc, 32);
    if (hq == 0) out[(size_t)row * 16 + c] = acc + bc2[c];
}

// ---------- launch ----------

extern "C" void kernel_launch(void* const* d_in, const int* in_sizes, int n_in,
                              void* d_out, int out_size, void* d_ws, size_t ws_size,
                              hipStream_t stream) {
    (void)in_sizes; (void)n_in; (void)out_size; (void)ws_size;
    const float* x   = (const float*)d_in[0];
    const float* W1  = (const float*)d_in[1];
    const float* b1  = (const float*)d_in[2];
    const float* W2  = (const float*)d_in[3];
    const float* b2  = (const float*)d_in[4];
    const float* Wc1 = (const float*)d_in[5];
    const float* bc1 = (const float*)d_in[6];
    const float* Wc2 = (const float*)d_in[7];
    const float* bc2 = (const float*)d_in[8];
    float* out = (float*)d_out;

    char* ws = (char*)d_ws;
    unsigned short* xb   = (unsigned short*)(ws);                  // 0..64 MB   x bf16 (live thru GEMM3)
    unsigned short* W1t  = (unsigned short*)(ws + (64ll  << 20));  // 64..72
    unsigned short* Tb   = (unsigned short*)(ws + (72ll  << 20));  // 72..88
    unsigned short* W2t  = (unsigned short*)(ws + (88ll  << 20));  // 88..96
    unsigned short* abf  = (unsigned short*)(ws + (96ll  << 20));  // 96..160    a bf16 (live thru GEMM3)
    unsigned short* Wc1t = (unsigned short*)(ws + (160ll << 20));  // 160..161
    float*          taub = (float*)         (ws + (162ll << 20));  // 162..162.03
    float*          P3   = (float*)         (ws + (168ll << 20));  // 168..200   GEMM3 partials (8x4MB)

    // fused cvt + transposes (one dispatch)
    k_pre<<<41472, 256, 0, stream>>>(x, xb, W1, W1t, W2, W2t, Wc1, Wc1t);

    // T = tanh(x @ W1 + b1)  [8192][1024] bf16 — XCD-swizzled, BK=64
    k_gemm_tanh<<<512, 512, 0, stream>>>(xb, W1t, b1, Tb, 1024, 4096, 4096, 4096);
    // a = T @ W2 + b2  [8192][4096] bf16 — XCD-swizzled (LBN=5)
    k_gemm<5><<<2048, 256, 0, stream>>>(Tb, W2t, b2, abf, 4096, 1024, 1024, 1024);
    // tau per row (sparsemax threshold)
    k_sparsemax_tau<<<2048, 256, 0, stream>>>(abf, taub);
    // P3[kz] = (x * max(a - tau, 0)) @ Wc1, split-K=8, gating in registers
    k_gemm3<<<dim3(64, 8), 256, 0, stream>>>(xb, abf, Wc1t, taub, P3);
    // out = relu(sum P3 + bc1) @ Wc2 + bc2
    k_final<<<2048, 256, 0, stream>>>(P3, bc1, Wc2, bc2, out);
}